// Round 1
// baseline (114.348 us; speedup 1.0000x reference)
//
#include <hip/hip_runtime.h>
#include <hip/hip_bf16.h>

// Sizes (fixed by the problem)
#define E_CNT 131072
#define NP_CNT 65536
#define NC_CNT 8192
#define D_P 80
#define D_C 48
#define D_ADD 16
#define D_HID 64
#define K1 1152   // 144*8
#define K2 512    // 64*8

typedef short bf16x8 __attribute__((ext_vector_type(8)));
typedef float f32x4 __attribute__((ext_vector_type(4)));

__device__ __forceinline__ unsigned short f2bf(float x){
  unsigned u = __builtin_bit_cast(unsigned, x);
  u = u + 0x7FFFu + ((u >> 16) & 1u);   // RNE
  return (unsigned short)(u >> 16);
}
__device__ __forceinline__ float bf2f(unsigned short b){
  unsigned u = ((unsigned)b) << 16;
  return __builtin_bit_cast(float, u);
}
__device__ __forceinline__ unsigned pk2(float a, float b){
  return (unsigned)f2bf(a) | ((unsigned)f2bf(b) << 16);
}
__device__ __forceinline__ float silu_f(float x){
  return x / (1.0f + __expf(-x));
}

// ---------------------------------------------------------------------------
// Kernel 1: W1 [144][8][64] f32 -> Wt1 [64][1152] bf16 ; W2 -> Wt2 [64][512]
// Wt[h][k] = W[k/8][k%8][h] = Wflat[k][h]
// ---------------------------------------------------------------------------
__global__ void prep_w_kernel(const float* __restrict__ W1, const float* __restrict__ W2,
                              unsigned short* __restrict__ wt1, unsigned short* __restrict__ wt2){
  int id = blockIdx.x * 256 + threadIdx.x;
  if (id < 64 * K1){
    int h = id / K1;
    int k = id - h * K1;
    wt1[id] = f2bf(W1[k * 64 + h]);
  } else {
    int id2 = id - 64 * K1;   // < 64*K2 by grid sizing
    int h = id2 / K2;
    int k = id2 - h * K2;
    wt2[id2] = f2bf(W2[k * 64 + h]);
  }
}

// ---------------------------------------------------------------------------
// Kernel 2: out[n, 0:80] = x_p[n]; out[n, 80:144] = 0   (float4 over rows of 36 quads)
// ---------------------------------------------------------------------------
__global__ void init_out_kernel(const float4* __restrict__ xp4, float4* __restrict__ out4){
  int i4 = blockIdx.x * 256 + threadIdx.x;    // 65536*36 quads
  int row = i4 / 36;
  int jq = i4 - row * 36;
  float4 z = make_float4(0.f, 0.f, 0.f, 0.f);
  out4[i4] = (jq < 20) ? xp4[row * 20 + jq] : z;
}

// ---------------------------------------------------------------------------
// GEMM kernels: out1[e,h] = sum_k xa[e,k] * Wt[h][k], xa[e, f*8+g] = x[e,f]*a[e,g]
// 256 threads = 4 waves; 256 edges/block; wave owns 64 edges x 64 h (4x4 16x16 tiles)
// K chunked by 64 (8 f x 8 g). LDS XOR-swizzled (16B slots, slot ^= row&7).
// ---------------------------------------------------------------------------
template<int KTOT, bool SECOND>
__global__ __launch_bounds__(256) void msg_gemm_kernel(
    const float* __restrict__ x_p, const float* __restrict__ x_c,
    const int* __restrict__ eidx, const float* __restrict__ ea,
    const float* __restrict__ addf,
    const unsigned short* __restrict__ wt, const float* __restrict__ bias,
    const unsigned short* __restrict__ m1in,
    unsigned short* __restrict__ m1out,
    float* __restrict__ out)
{
  __shared__ unsigned int s_xa[256 * 32];  // [256 edges][64 bf16] = 32 KB, swizzled
  __shared__ unsigned int s_w [64 * 32];   // [64 h][64 bf16]     =  8 KB, swizzled
  __shared__ int s_dst[256];

  const int t    = threadIdx.x;
  const int e    = blockIdx.x * 256 + t;
  const int lane = t & 63;
  const int wv   = t >> 6;
  const int l15  = lane & 15;
  const int q    = lane >> 4;

  // per-edge attrs in registers (reused every chunk)
  float af[8];
  {
    const float4* ap = reinterpret_cast<const float4*>(ea + (size_t)e * 8);
    float4 a0 = ap[0], a1 = ap[1];
    af[0] = a0.x; af[1] = a0.y; af[2] = a0.z; af[3] = a0.w;
    af[4] = a1.x; af[5] = a1.y; af[6] = a1.z; af[7] = a1.w;
  }
  const int dstI = eidx[E_CNT + e];
  int srcI = 0;
  if constexpr (!SECOND) srcI = eidx[e];
  if constexpr (SECOND)  s_dst[t] = dstI;

  f32x4 acc[4][4];
  #pragma unroll
  for (int i = 0; i < 4; ++i)
    #pragma unroll
    for (int j = 0; j < 4; ++j)
      acc[i][j] = f32x4{0.f, 0.f, 0.f, 0.f};

  constexpr int NCH = KTOT / 64;
  for (int c = 0; c < NCH; ++c){
    // ---- build xa chunk: this thread owns edge-row t, f in [c*8, c*8+8)
    float xv[8];
    if constexpr (!SECOND){
      const int fb = c * 8;
      if (fb < D_P){
        const float4* p = reinterpret_cast<const float4*>(x_p + (size_t)dstI * D_P + fb);
        float4 v0 = p[0], v1 = p[1];
        xv[0]=v0.x; xv[1]=v0.y; xv[2]=v0.z; xv[3]=v0.w;
        xv[4]=v1.x; xv[5]=v1.y; xv[6]=v1.z; xv[7]=v1.w;
      } else if (fb < D_P + D_C){
        const float4* p = reinterpret_cast<const float4*>(x_c + (size_t)srcI * D_C + (fb - D_P));
        float4 v0 = p[0], v1 = p[1];
        xv[0]=v0.x; xv[1]=v0.y; xv[2]=v0.z; xv[3]=v0.w;
        xv[4]=v1.x; xv[5]=v1.y; xv[6]=v1.z; xv[7]=v1.w;
      } else {
        const float4* p = reinterpret_cast<const float4*>(addf + (size_t)e * D_ADD + (fb - D_P - D_C));
        float4 v0 = p[0], v1 = p[1];
        xv[0]=v0.x; xv[1]=v0.y; xv[2]=v0.z; xv[3]=v0.w;
        xv[4]=v1.x; xv[5]=v1.y; xv[6]=v1.z; xv[7]=v1.w;
      }
    } else {
      const uint4 mv = *reinterpret_cast<const uint4*>(m1in + (size_t)e * 64 + c * 8);
      const unsigned short* ms = reinterpret_cast<const unsigned short*>(&mv);
      #pragma unroll
      for (int fl = 0; fl < 8; ++fl) xv[fl] = bf2f(ms[fl]);
    }
    #pragma unroll
    for (int fl = 0; fl < 8; ++fl){
      float x = xv[fl];
      uint4 wv4;
      wv4.x = pk2(x * af[0], x * af[1]);
      wv4.y = pk2(x * af[2], x * af[3]);
      wv4.z = pk2(x * af[4], x * af[5]);
      wv4.w = pk2(x * af[6], x * af[7]);
      const int slot = fl ^ (t & 7);
      *reinterpret_cast<uint4*>(&s_xa[t * 32 + slot * 4]) = wv4;
    }
    // ---- stage W chunk [64 h][64 k]
    {
      const int h = t >> 2, part = t & 3;
      const unsigned short* gw = wt + (size_t)h * KTOT + c * 64;
      #pragma unroll
      for (int qq = 0; qq < 2; ++qq){
        const int sl = part * 2 + qq;
        uint4 v = *reinterpret_cast<const uint4*>(gw + sl * 8);
        const int phys = sl ^ (h & 7);
        *reinterpret_cast<uint4*>(&s_w[h * 32 + phys * 4]) = v;
      }
    }
    __syncthreads();
    // ---- MFMA: 2 k-steps of 32
    #pragma unroll
    for (int ks = 0; ks < 2; ++ks){
      bf16x8 Af[4], Bf[4];
      #pragma unroll
      for (int mt = 0; mt < 4; ++mt){
        const int er = wv * 64 + mt * 16 + l15;
        const int slot = (ks * 4 + q) ^ (er & 7);
        Af[mt] = __builtin_bit_cast(bf16x8, *reinterpret_cast<const uint4*>(&s_xa[er * 32 + slot * 4]));
      }
      #pragma unroll
      for (int nt = 0; nt < 4; ++nt){
        const int hr = nt * 16 + l15;
        const int slot = (ks * 4 + q) ^ (hr & 7);
        Bf[nt] = __builtin_bit_cast(bf16x8, *reinterpret_cast<const uint4*>(&s_w[hr * 32 + slot * 4]));
      }
      #pragma unroll
      for (int mt = 0; mt < 4; ++mt)
        #pragma unroll
        for (int nt = 0; nt < 4; ++nt)
          acc[mt][nt] = __builtin_amdgcn_mfma_f32_16x16x32_bf16(Af[mt], Bf[nt], acc[mt][nt], 0, 0, 0);
    }
    __syncthreads();
  }

  // ---- epilogue: +bias, SiLU; C/D layout: col = lane&15, row = (lane>>4)*4 + r
  float bv[4];
  #pragma unroll
  for (int nt = 0; nt < 4; ++nt) bv[nt] = bias[nt * 16 + l15];

  #pragma unroll
  for (int mt = 0; mt < 4; ++mt){
    #pragma unroll
    for (int nt = 0; nt < 4; ++nt){
      #pragma unroll
      for (int r = 0; r < 4; ++r){
        float x = acc[mt][nt][r] + bv[nt];
        float s = silu_f(x);
        const int er = wv * 64 + mt * 16 + q * 4 + r;
        if constexpr (!SECOND){
          m1out[(size_t)(blockIdx.x * 256 + er) * 64 + nt * 16 + l15] = f2bf(s);
        } else {
          unsafeAtomicAdd(out + (size_t)s_dst[er] * 144 + 80 + nt * 16 + l15, s);
        }
      }
    }
  }
}

extern "C" void kernel_launch(void* const* d_in, const int* in_sizes, int n_in,
                              void* d_out, int out_size, void* d_ws, size_t ws_size,
                              hipStream_t stream){
  const float* x_p  = (const float*)d_in[0];
  const float* x_c  = (const float*)d_in[1];
  const int*   eidx = (const int*)d_in[2];
  const float* ea   = (const float*)d_in[3];
  // d_in[4] = batch (unused, norm=None)
  const float* addf = (const float*)d_in[5];
  const float* W1   = (const float*)d_in[6];
  const float* b1   = (const float*)d_in[7];
  const float* W2   = (const float*)d_in[8];
  const float* b2   = (const float*)d_in[9];
  float* out = (float*)d_out;

  char* ws = (char*)d_ws;
  unsigned short* wt1 = (unsigned short*)(ws);             // 147456 B
  unsigned short* wt2 = (unsigned short*)(ws + 163840);    //  65536 B
  unsigned short* m1  = (unsigned short*)(ws + 262144);    // 16.78 MB (E*64 bf16)

  prep_w_kernel<<<(64 * K1 + 64 * K2) / 256, 256, 0, stream>>>(W1, W2, wt1, wt2);
  init_out_kernel<<<(NP_CNT * 36) / 256, 256, 0, stream>>>((const float4*)x_p, (float4*)out);
  msg_gemm_kernel<K1, false><<<E_CNT / 256, 256, 0, stream>>>(
      x_p, x_c, eidx, ea, addf, wt1, b1, nullptr, m1, nullptr);
  msg_gemm_kernel<K2, true><<<E_CNT / 256, 256, 0, stream>>>(
      x_p, x_c, eidx, ea, addf, wt2, b2, m1, nullptr, out);
}

// Round 3
// 91.842 us; speedup vs baseline: 1.2450x; 1.2450x over previous
//
#include <hip/hip_runtime.h>
#include <hip/hip_bf16.h>

// Sizes (fixed by the problem)
#define E_CNT 131072
#define NP_CNT 65536
#define D_P 80
#define D_C 48
#define D_ADD 16
#define K1 1152   // 144*8
#define K2 512    // 64*8

typedef _Float16 f16x8 __attribute__((ext_vector_type(8)));
typedef _Float16 f16x4 __attribute__((ext_vector_type(4)));
typedef _Float16 f16x2 __attribute__((ext_vector_type(2)));
typedef float f32x4 __attribute__((ext_vector_type(4)));

__device__ __forceinline__ float silu_f(float x){
  return x / (1.0f + __expf(-x));
}
__device__ __forceinline__ f16x2 pkrtz(float a, float b){
  return __builtin_bit_cast(f16x2, __builtin_amdgcn_cvt_pkrtz(a, b));
}

// ---------------------------------------------------------------------------
// Kernel 1: W1 [144][8][64] f32 -> Wt1 [64][1152] f16 ; W2 -> Wt2 [64][512]
// Wt[h][k] = Wflat[k][h]
// ---------------------------------------------------------------------------
__global__ void prep_w_kernel(const float* __restrict__ W1, const float* __restrict__ W2,
                              _Float16* __restrict__ wt1, _Float16* __restrict__ wt2){
  int id = blockIdx.x * 256 + threadIdx.x;
  if (id < 64 * K1){
    int h = id / K1;
    int k = id - h * K1;
    wt1[id] = (_Float16)W1[k * 64 + h];
  } else {
    int id2 = id - 64 * K1;
    int h = id2 / K2;
    int k = id2 - h * K2;
    wt2[id2] = (_Float16)W2[k * 64 + h];
  }
}

// ---------------------------------------------------------------------------
// Kernel 2: out[n, 0:80] = x_p[n]; out[n, 80:144] = 0
// ---------------------------------------------------------------------------
__global__ void init_out_kernel(const float4* __restrict__ xp4, float4* __restrict__ out4){
  int i4 = blockIdx.x * 256 + threadIdx.x;
  int row = i4 / 36;
  int jq = i4 - row * 36;
  float4 z = make_float4(0.f, 0.f, 0.f, 0.f);
  out4[i4] = (jq < 20) ? xp4[row * 20 + jq] : z;
}

// ---------------------------------------------------------------------------
// GEMM: out[e,h] = sum_k xa[e,k] * Wt[h][k], xa[e, f*8+g] = x[e,f]*a[e,g] (fp16)
// 256 threads = 4 waves; 128 edges/block (2 threads build each edge row);
// wave owns 32 edges x 64 h (2x4 tiles of 16x16). K chunked by 64 (8f x 8g).
// LDS XOR-swizzled in 16B slots: slot ^= row&7.
// ---------------------------------------------------------------------------
template<int KTOT, bool SECOND>
__global__ __launch_bounds__(256, 4) void msg_gemm_kernel(
    const float* __restrict__ x_p, const float* __restrict__ x_c,
    const int* __restrict__ eidx, const float* __restrict__ ea,
    const float* __restrict__ addf,
    const _Float16* __restrict__ wt, const float* __restrict__ bias,
    const _Float16* __restrict__ m1in,
    _Float16* __restrict__ m1out,
    float* __restrict__ out)
{
  __shared__ unsigned int s_xa[128 * 32];  // [128 edges][64 f16] = 16 KB, swizzled
  __shared__ unsigned int s_w [64 * 32];   // [64 h][64 f16]     =  8 KB, swizzled
  __shared__ int s_dst[128];

  const int t    = threadIdx.x;
  const int er   = t >> 1;                 // edge row within block, 0..127
  const int hh   = t & 1;                  // which 4-f half this thread builds
  const int e    = blockIdx.x * 128 + er;
  const int lane = t & 63;
  const int wv   = t >> 6;
  const int l15  = lane & 15;
  const int q    = lane >> 4;

  // edge_attr row -> 4 packed half2 (reused every chunk)
  f16x2 apk[4];
  {
    const float4* ap = reinterpret_cast<const float4*>(ea + (size_t)e * 8);
    float4 a0 = ap[0], a1 = ap[1];
    apk[0] = pkrtz(a0.x, a0.y);
    apk[1] = pkrtz(a0.z, a0.w);
    apk[2] = pkrtz(a1.x, a1.y);
    apk[3] = pkrtz(a1.z, a1.w);
  }
  const int dstI = eidx[E_CNT + e];
  int srcI = 0;
  if constexpr (!SECOND) srcI = eidx[e];
  if constexpr (SECOND)  s_dst[er] = dstI;

  f32x4 acc[2][4];
  #pragma unroll
  for (int i = 0; i < 2; ++i)
    #pragma unroll
    for (int j = 0; j < 4; ++j)
      acc[i][j] = f32x4{0.f, 0.f, 0.f, 0.f};

  constexpr int NCH = KTOT / 64;
  for (int c = 0; c < NCH; ++c){
    // ---- W chunk global loads issued first (latency overlaps the xa build)
    uint4 wreg[2];
    const int wh = t >> 2, wpart = t & 3;
    {
      const _Float16* gw = wt + (size_t)wh * KTOT + c * 64;
      #pragma unroll
      for (int qq = 0; qq < 2; ++qq)
        wreg[qq] = *reinterpret_cast<const uint4*>(gw + (wpart * 2 + qq) * 8);
    }
    // ---- build xa quarter-row: f-broadcast halves, packed products
    f16x2 xbc[4];
    if constexpr (!SECOND){
      const int fb = c * 8 + hh * 4;
      const float* src;
      if (fb < D_P)            src = x_p  + (size_t)dstI * D_P   + fb;
      else if (fb < D_P + D_C) src = x_c  + (size_t)srcI * D_C   + (fb - D_P);
      else                     src = addf + (size_t)e    * D_ADD + (fb - D_P - D_C);
      float4 v = *reinterpret_cast<const float4*>(src);
      xbc[0] = pkrtz(v.x, v.x);
      xbc[1] = pkrtz(v.y, v.y);
      xbc[2] = pkrtz(v.z, v.z);
      xbc[3] = pkrtz(v.w, v.w);
    } else {
      const _Float16* mp = m1in + (size_t)e * 64 + c * 8 + hh * 4;
      f16x4 mh = __builtin_bit_cast(f16x4, *reinterpret_cast<const uint2*>(mp));
      #pragma unroll
      for (int j = 0; j < 4; ++j){ xbc[j] = f16x2{mh[j], mh[j]}; }
    }
    #pragma unroll
    for (int fl = 0; fl < 4; ++fl){
      f16x2 p0 = xbc[fl] * apk[0];
      f16x2 p1 = xbc[fl] * apk[1];
      f16x2 p2 = xbc[fl] * apk[2];
      f16x2 p3 = xbc[fl] * apk[3];
      uint4 w4;
      w4.x = __builtin_bit_cast(unsigned, p0);
      w4.y = __builtin_bit_cast(unsigned, p1);
      w4.z = __builtin_bit_cast(unsigned, p2);
      w4.w = __builtin_bit_cast(unsigned, p3);
      const int slot = (hh * 4 + fl) ^ (er & 7);
      *reinterpret_cast<uint4*>(&s_xa[er * 32 + slot * 4]) = w4;
    }
    // ---- W chunk -> LDS
    #pragma unroll
    for (int qq = 0; qq < 2; ++qq){
      const int sl = wpart * 2 + qq;
      const int phys = sl ^ (wh & 7);
      *reinterpret_cast<uint4*>(&s_w[wh * 32 + phys * 4]) = wreg[qq];
    }
    __syncthreads();
    // ---- MFMA: 2 k-steps of 32
    #pragma unroll
    for (int ks = 0; ks < 2; ++ks){
      f16x8 Af[2], Bf[4];
      #pragma unroll
      for (int mt = 0; mt < 2; ++mt){
        const int erow = wv * 32 + mt * 16 + l15;
        const int slot = (ks * 4 + q) ^ (erow & 7);
        Af[mt] = __builtin_bit_cast(f16x8, *reinterpret_cast<const uint4*>(&s_xa[erow * 32 + slot * 4]));
      }
      #pragma unroll
      for (int nt = 0; nt < 4; ++nt){
        const int hr = nt * 16 + l15;
        const int slot = (ks * 4 + q) ^ (hr & 7);
        Bf[nt] = __builtin_bit_cast(f16x8, *reinterpret_cast<const uint4*>(&s_w[hr * 32 + slot * 4]));
      }
      #pragma unroll
      for (int mt = 0; mt < 2; ++mt)
        #pragma unroll
        for (int nt = 0; nt < 4; ++nt)
          acc[mt][nt] = __builtin_amdgcn_mfma_f32_16x16x32_f16(Af[mt], Bf[nt], acc[mt][nt], 0, 0, 0);
    }
    __syncthreads();
  }

  // ---- epilogue: +bias, SiLU; C/D: col = lane&15, row = (lane>>4)*4 + r
  float bv[4];
  #pragma unroll
  for (int nt = 0; nt < 4; ++nt) bv[nt] = bias[nt * 16 + l15];

  #pragma unroll
  for (int mt = 0; mt < 2; ++mt){
    #pragma unroll
    for (int nt = 0; nt < 4; ++nt){
      #pragma unroll
      for (int r = 0; r < 4; ++r){
        float x = acc[mt][nt][r] + bv[nt];
        float s = silu_f(x);
        const int erow = wv * 32 + mt * 16 + q * 4 + r;
        if constexpr (!SECOND){
          m1out[(size_t)(blockIdx.x * 128 + erow) * 64 + nt * 16 + l15] = (_Float16)s;
        } else {
          unsafeAtomicAdd(out + (size_t)s_dst[erow] * 144 + 80 + nt * 16 + l15, s);
        }
      }
    }
  }
}

extern "C" void kernel_launch(void* const* d_in, const int* in_sizes, int n_in,
                              void* d_out, int out_size, void* d_ws, size_t ws_size,
                              hipStream_t stream){
  const float* x_p  = (const float*)d_in[0];
  const float* x_c  = (const float*)d_in[1];
  const int*   eidx = (const int*)d_in[2];
  const float* ea   = (const float*)d_in[3];
  // d_in[4] = batch (unused)
  const float* addf = (const float*)d_in[5];
  const float* W1   = (const float*)d_in[6];
  const float* b1   = (const float*)d_in[7];
  const float* W2   = (const float*)d_in[8];
  const float* b2   = (const float*)d_in[9];
  float* out = (float*)d_out;

  char* ws = (char*)d_ws;
  _Float16* wt1 = (_Float16*)(ws);             // 147456 B
  _Float16* wt2 = (_Float16*)(ws + 163840);    //  65536 B
  _Float16* m1  = (_Float16*)(ws + 262144);    // 16.78 MB (E*64 f16)

  prep_w_kernel<<<(64 * K1 + 64 * K2) / 256, 256, 0, stream>>>(W1, W2, wt1, wt2);
  init_out_kernel<<<(NP_CNT * 36) / 256, 256, 0, stream>>>((const float4*)x_p, (float4*)out);
  msg_gemm_kernel<K1, false><<<E_CNT / 128, 256, 0, stream>>>(
      x_p, x_c, eidx, ea, addf, wt1, b1, nullptr, m1, nullptr);
  msg_gemm_kernel<K2, true><<<E_CNT / 128, 256, 0, stream>>>(
      x_p, x_c, eidx, ea, addf, wt2, b2, m1, nullptr, out);
}